// Round 12
// baseline (1227.588 us; speedup 1.0000x reference)
//
#include <hip/hip_runtime.h>
#include <hip/hip_bf16.h>

#define NN 20000
#define NE 320000
#define HD 128
#define IND 16
#define OUTD 16
#define NL 4
#define LN_EPS 1e-5f
#define LDA 136  // LDS row stride in shorts (272B): 16B-aligned rows, ~2-way banks

typedef __attribute__((ext_vector_type(8))) short bf16x8;
typedef __attribute__((ext_vector_type(4))) float f32x4;

__device__ __forceinline__ unsigned short f2b(float f) {
  __hip_bfloat16 h = __float2bfloat16(f);  // RNE; compiler packs v_cvt_pk_bf16_f32
  unsigned short u;
  __builtin_memcpy(&u, &h, 2);
  return u;
}
__device__ __forceinline__ float b2f(unsigned int lo16) {
  union { unsigned int u; float f; } v; v.u = lo16 << 16; return v.f;
}

// ---------------- prep kernels ----------------

__global__ void prep_zero_k(const float* __restrict__ xin, float* __restrict__ xf,
                            float* __restrict__ cnt, int* __restrict__ deg) {
  int i = blockIdx.x * 256 + threadIdx.x;
  if (i < NN * 3) xf[i] = xin[i];
  if (i < NN) { cnt[i] = 0.f; deg[i] = 0; }
}

__global__ void count_k(const int* __restrict__ edges, float* __restrict__ cnt,
                        int* __restrict__ deg) {
  int e = blockIdx.x * 256 + threadIdx.x;
  if (e < NE) {
    atomicAdd(&cnt[edges[e]], 1.f);
    atomicAdd(&deg[edges[NE + e]], 1);
  }
}

__global__ void inv_k(float* __restrict__ cnt) {
  int n = blockIdx.x * 256 + threadIdx.x;
  if (n < NN) { float c = cnt[n]; cnt[n] = (c > 0.f) ? 1.f / c : 0.f; }
}

__global__ void scan_k(const int* __restrict__ deg, int* __restrict__ rowptr,
                       int* __restrict__ cursor) {
  __shared__ int part[256];
  const int tid = threadIdx.x;
  const int base = tid * 79;
  int s = 0;
  for (int t = 0; t < 79; ++t) { int idx = base + t; if (idx < NN) s += deg[idx]; }
  part[tid] = s;
  __syncthreads();
  for (int off = 1; off < 256; off <<= 1) {
    int v = (tid >= off) ? part[tid - off] : 0;
    __syncthreads();
    part[tid] += v;
    __syncthreads();
  }
  int run = (tid == 0) ? 0 : part[tid - 1];
  for (int t = 0; t < 79; ++t) {
    int idx = base + t;
    if (idx < NN) { rowptr[idx] = run; cursor[idx] = run; run += deg[idx]; }
  }
  if (tid == 255) rowptr[NN] = run;
}

__global__ void scatter_k(const int* __restrict__ edges, int* __restrict__ cursor,
                          int* __restrict__ eids) {
  int e = blockIdx.x * 256 + threadIdx.x;
  if (e < NE) {
    int d = edges[NE + e];
    int pos = atomicAdd(&cursor[d], 1);
    eids[pos] = e;
  }
}

// weights: src f32 [NL][Kreal][128] -> dst bf16 tiled [NL][KT][128][32]
__global__ void prep_w_k(const float* __restrict__ src, unsigned short* __restrict__ dst,
                         int KT, int Kreal) {
  int i = blockIdx.x * 256 + threadIdx.x;
  int total = NL * KT * 4096;
  if (i >= total) return;
  int kk = i & 31;
  int c = (i >> 5) & 127;
  int lkt = i >> 12;
  int kt = lkt % KT;
  int l = lkt / KT;
  int k = kt * 32 + kk;
  float v = (k < Kreal) ? src[((size_t)l * Kreal + k) * HD + c] : 0.f;
  dst[i] = f2b(v);
}

__global__ void emb_k(const float* __restrict__ hin, const float* __restrict__ w,
                      const float* __restrict__ b, float* __restrict__ hf,
                      unsigned short* __restrict__ hb) {
  int i = blockIdx.x * 256 + threadIdx.x;
  if (i >= NN * HD) return;
  int n = i >> 7, c = i & 127;
  float acc = b[c];
#pragma unroll
  for (int k = 0; k < IND; ++k) acc += hin[n * IND + k] * w[k * HD + c];
  hf[i] = acc;
  hb[i] = f2b(acc);
}

__global__ void prepd_k(const float* __restrict__ xf, const int* __restrict__ edges,
                        const float* __restrict__ ea, float* __restrict__ dvec,
                        unsigned short* __restrict__ e8) {
  int e = blockIdx.x * 256 + threadIdx.x;
  if (e >= NE) return;
  int j = edges[e], i = edges[NE + e];
  float dx = xf[i * 3 + 0] - xf[j * 3 + 0];
  float dy = xf[i * 3 + 1] - xf[j * 3 + 1];
  float dz = xf[i * 3 + 2] - xf[j * 3 + 2];
  float d2 = dx * dx + dy * dy + dz * dz;
  dvec[e * 4 + 0] = dx; dvec[e * 4 + 1] = dy; dvec[e * 4 + 2] = dz; dvec[e * 4 + 3] = d2;
  e8[e * 8 + 0] = f2b(d2);
#pragma unroll
  for (int a = 0; a < 4; ++a) e8[e * 8 + 1 + a] = f2b(ea[e * 4 + a]);
  e8[e * 8 + 5] = 0; e8[e * 8 + 6] = 0; e8[e * 8 + 7] = 0;
}

__global__ void outproj_k(const float* __restrict__ hf, const float* __restrict__ w,
                          const float* __restrict__ b, float* __restrict__ out) {
  int i = blockIdx.x * 256 + threadIdx.x;
  if (i >= NN * OUTD) return;
  int n = i >> 4, o = i & 15;
  float acc = b[o];
#pragma unroll 8
  for (int k = 0; k < HD; ++k) acc += hf[(size_t)n * HD + k] * w[k * OUTD + o];
  out[NN * 3 + i] = acc;
}

__global__ void xcopy_k(const float* __restrict__ xf, float* __restrict__ out) {
  int i = blockIdx.x * 256 + threadIdx.x;
  if (i < NN * 3) out[i] = xf[i];
}

// ---------------- CSR gather: agg_h (bf16 out) + agg_x + x update ----------------

__global__ __launch_bounds__(256) void gather_k(const unsigned short* __restrict__ tbuf,
                                                const float* __restrict__ sc,
                                                const float* __restrict__ dvec,
                                                const int* __restrict__ rowptr,
                                                const int* __restrict__ eids,
                                                const float* __restrict__ cinv,
                                                unsigned short* __restrict__ agghb,
                                                float* __restrict__ xf) {
  const int n = blockIdx.x * 4 + (threadIdx.x >> 6);
  if (n >= NN) return;
  const int lane = threadIdx.x & 63;
  const int s = rowptr[n], e = rowptr[n + 1];
  float a0 = 0.f, a1 = 0.f, xa = 0.f;
  for (int t = s; t < e; ++t) {
    const int eid = eids[t];
    const unsigned int v = *(const unsigned int*)(tbuf + (size_t)eid * HD + lane * 2);
    a0 += b2f(v & 0xffffu);
    a1 += b2f(v >> 16);
    if (lane < 3) xa += dvec[(size_t)eid * 4 + lane] * sc[eid];
  }
  const unsigned int pk = (unsigned int)f2b(a0) | ((unsigned int)f2b(a1) << 16);
  *(unsigned int*)(agghb + (size_t)n * HD + lane * 2) = pk;
  if (lane < 3) xf[n * 3 + lane] += xa * cinv[n];
}

// ---------------- wave-strip GEMM pieces (wave owns 32 rows x 128 cols) ----------------

__device__ __forceinline__ void mfma_w(const bf16x8 (&A)[2], const bf16x8 (&B)[8],
                                       f32x4 (&acc)[2][8]) {
#pragma unroll
  for (int mf = 0; mf < 2; ++mf)
#pragma unroll
    for (int nf = 0; nf < 8; ++nf)
      acc[mf][nf] = __builtin_amdgcn_mfma_f32_16x16x32_bf16(A[mf], B[nf], acc[mf][nf], 0, 0, 0);
}

#define ZACC()                                          \
  _Pragma("unroll") for (int a_ = 0; a_ < 2; ++a_)      \
  _Pragma("unroll") for (int b_ = 0; b_ < 8; ++b_)      \
      acc[a_][b_] = (f32x4){0.f, 0.f, 0.f, 0.f}

// depth-1-prefetch double-buffered K pipeline; audited: kt consumed exactly once.
#define GEMM_PIPE(NKT, LD)                              \
  LD(0, A0, B0);                                        \
  _Pragma("unroll") for (int kt = 0; kt < (NKT); ++kt) {\
    if ((kt & 1) == 0) {                                \
      if (kt + 1 < (NKT)) LD(kt + 1, A1, B1);           \
      mfma_w(A0, B0, acc);                              \
    } else {                                            \
      if (kt + 1 < (NKT)) LD(kt + 1, A0, B0);           \
      mfma_w(A1, B1, acc);                              \
    }                                                   \
  }

// bias + row-LayerNorm(128) + SiLU, fully wave-local (no LDS, no barrier).
__device__ __forceinline__ void ln_silu_w(f32x4 (&acc)[2][8], const float* bias,
                                          const float* g, const float* bb, int lid) {
  float biasc[8], gc[8], bbc[8];
#pragma unroll
  for (int nf = 0; nf < 8; ++nf) {
    const int c = nf * 16 + lid;
    biasc[nf] = bias[c]; gc[nf] = g[c]; bbc[nf] = bb[c];
  }
#pragma unroll
  for (int mf = 0; mf < 2; ++mf)
#pragma unroll
    for (int nf = 0; nf < 8; ++nf)
#pragma unroll
      for (int rg = 0; rg < 4; ++rg) acc[mf][nf][rg] += biasc[nf];

  float s_[2][4], ss_[2][4];
#pragma unroll
  for (int mf = 0; mf < 2; ++mf)
#pragma unroll
    for (int rg = 0; rg < 4; ++rg) {
      float a = 0.f, b = 0.f;
#pragma unroll
      for (int nf = 0; nf < 8; ++nf) { float v = acc[mf][nf][rg]; a += v; b += v * v; }
      s_[mf][rg] = a; ss_[mf][rg] = b;
    }
#pragma unroll
  for (int m = 1; m < 16; m <<= 1) {
#pragma unroll
    for (int mf = 0; mf < 2; ++mf)
#pragma unroll
      for (int rg = 0; rg < 4; ++rg) {
        s_[mf][rg] += __shfl_xor(s_[mf][rg], m);
        ss_[mf][rg] += __shfl_xor(ss_[mf][rg], m);
      }
  }
#pragma unroll
  for (int mf = 0; mf < 2; ++mf)
#pragma unroll
    for (int rg = 0; rg < 4; ++rg) {
      const float mu = s_[mf][rg] * (1.f / HD);
      const float var = ss_[mf][rg] * (1.f / HD) - mu * mu;
      const float rstd = rsqrtf(var + LN_EPS);
#pragma unroll
      for (int nf = 0; nf < 8; ++nf) {
        float v = acc[mf][nf][rg];
        v = (v - mu) * rstd * gc[nf] + bbc[nf];
        acc[mf][nf][rg] = v / (1.f + __expf(-v));
      }
    }
}

// write this wave's 32x128 C strip (bf16) into its private LDS rows
__device__ __forceinline__ void write_strip(const f32x4 (&acc)[2][8], unsigned short* At,
                                            int rbase, int lid, int q) {
#pragma unroll
  for (int mf = 0; mf < 2; ++mf)
#pragma unroll
    for (int rg = 0; rg < 4; ++rg) {
      const int row = rbase + mf * 16 + q * 4 + rg;
#pragma unroll
      for (int nf = 0; nf < 8; ++nf)
        At[row * LDA + nf * 16 + lid] = f2b(acc[mf][nf][rg]);
    }
}

// ---------------- fused edge kernel (ZERO barriers) ----------------

struct EP {
  const unsigned short* hb;
  const unsigned short* e8;
  const int* edges;
  const unsigned short *w1, *w2, *w3;
  const float *b1, *g1, *bb1, *b2, *g2, *bb2, *b3, *g3, *bb3;
  const float *w4, *b4;
  unsigned short* tbuf;
  float* sc;
};

__global__ __launch_bounds__(256, 3) void edge_k(EP p) {
  __shared__ __align__(16) unsigned short At[128 * LDA];

  const int tid = threadIdx.x, lane = tid & 63, lid = lane & 15, q = lane >> 4;
  const int wave = tid >> 6;
  const int rbase = wave * 32;
  const int row0 = blockIdx.x * 128;

  int ei[2], ej[2];
#pragma unroll
  for (int mf = 0; mf < 2; ++mf) {
    const int r = row0 + rbase + mf * 16 + lid;
    ei[mf] = p.edges[NE + r];
    ej[mf] = p.edges[r];
  }

  const bf16x8 zv = {0, 0, 0, 0, 0, 0, 0, 0};

  auto LD1 = [&](int kt, bf16x8 (&A)[2], bf16x8 (&B)[8]) {
#pragma unroll
    for (int mf = 0; mf < 2; ++mf) {
      if (kt < 4)
        A[mf] = *(const bf16x8*)(p.hb + (size_t)ei[mf] * HD + kt * 32 + q * 8);
      else if (kt < 8)
        A[mf] = *(const bf16x8*)(p.hb + (size_t)ej[mf] * HD + (kt - 4) * 32 + q * 8);
      else if (q == 0)
        A[mf] = *(const bf16x8*)(p.e8 + (size_t)(row0 + rbase + mf * 16 + lid) * 8);
      else
        A[mf] = zv;
    }
#pragma unroll
    for (int nf = 0; nf < 8; ++nf)
      B[nf] = *(const bf16x8*)(p.w1 + (size_t)kt * 4096 + (nf * 16 + lid) * 32 + q * 8);
  };
  auto LDW = [&](const unsigned short* wt, int kt, bf16x8 (&A)[2], bf16x8 (&B)[8]) {
#pragma unroll
    for (int mf = 0; mf < 2; ++mf)
      A[mf] = *(const bf16x8*)&At[(rbase + mf * 16 + lid) * LDA + kt * 32 + q * 8];
#pragma unroll
    for (int nf = 0; nf < 8; ++nf)
      B[nf] = *(const bf16x8*)(wt + (size_t)kt * 4096 + (nf * 16 + lid) * 32 + q * 8);
  };
  auto LD2 = [&](int kt, bf16x8 (&A)[2], bf16x8 (&B)[8]) { LDW(p.w2, kt, A, B); };
  auto LD3 = [&](int kt, bf16x8 (&A)[2], bf16x8 (&B)[8]) { LDW(p.w3, kt, A, B); };

  f32x4 acc[2][8];
  bf16x8 A0[2], B0[8], A1[2], B1[8];

  // GEMM1: K=288 (9 k-tiles)
  ZACC();
  GEMM_PIPE(9, LD1);
  ln_silu_w(acc, p.b1, p.g1, p.bb1, lid);
  write_strip(acc, At, rbase, lid, q);  // t -> wave-private LDS rows

  // GEMM2: K=128
  ZACC();
  GEMM_PIPE(4, LD2);
  ln_silu_w(acc, p.b2, p.g2, p.bb2, lid);
  write_strip(acc, At, rbase, lid, q);  // mh -> LDS

  // mh copy-out: wave copies its own 32 rows (16B granules, coalesced)
#pragma unroll
  for (int it = 0; it < 8; ++it) {
    const int idx = it * 64 + lane;
    const int row = idx >> 4, sl = idx & 15;
    const uint4 v = *(const uint4*)&At[(rbase + row) * LDA + sl * 8];
    *(uint4*)(p.tbuf + (size_t)(row0 + rbase + row) * HD + sl * 8) = v;
  }

  // GEMM3: K=128
  ZACC();
  GEMM_PIPE(4, LD3);
  ln_silu_w(acc, p.b3, p.g3, p.bb3, lid);

  // sc = dot(t2_row, w4) + b4 — wave-local reduce, direct store
  float w4c[8];
#pragma unroll
  for (int nf = 0; nf < 8; ++nf) w4c[nf] = p.w4[nf * 16 + lid];
  float dp[2][4];
#pragma unroll
  for (int mf = 0; mf < 2; ++mf)
#pragma unroll
    for (int rg = 0; rg < 4; ++rg) {
      float a = 0.f;
#pragma unroll
      for (int nf = 0; nf < 8; ++nf) a += acc[mf][nf][rg] * w4c[nf];
      dp[mf][rg] = a;
    }
#pragma unroll
  for (int m = 1; m < 16; m <<= 1) {
#pragma unroll
    for (int mf = 0; mf < 2; ++mf)
#pragma unroll
      for (int rg = 0; rg < 4; ++rg) dp[mf][rg] += __shfl_xor(dp[mf][rg], m);
  }
  if (lid == 0) {
    const float b4 = p.b4[0];
#pragma unroll
    for (int mf = 0; mf < 2; ++mf)
#pragma unroll
      for (int rg = 0; rg < 4; ++rg)
        p.sc[row0 + rbase + mf * 16 + q * 4 + rg] = dp[mf][rg] + b4;
  }
}

// ---------------- fused node kernel (ZERO barriers, 64-row blocks, bf16 A) ----------------

struct NP {
  const float* hf;
  const unsigned short* hb;
  const unsigned short* agghb;
  const unsigned short *w4t, *w5t;
  const float *b1, *g1, *bb1, *b5;
  float* hf_out;
  unsigned short* hb_out;
};

__global__ __launch_bounds__(128, 3) void node_k(NP p) {
  __shared__ __align__(16) unsigned short At[64 * LDA];

  const int tid = threadIdx.x, lane = tid & 63, lid = lane & 15, q = lane >> 4;
  const int wave = tid >> 6;  // 0..1
  const int rbase = wave * 32;
  const int row0 = blockIdx.x * 64;

  int nrow[2];
  bool okm[2];
#pragma unroll
  for (int mf = 0; mf < 2; ++mf) {
    nrow[mf] = row0 + rbase + mf * 16 + lid;
    okm[mf] = nrow[mf] < NN;
  }

  const bf16x8 zv = {0, 0, 0, 0, 0, 0, 0, 0};

  auto LD4 = [&](int kt, bf16x8 (&A)[2], bf16x8 (&B)[8]) {
#pragma unroll
    for (int mf = 0; mf < 2; ++mf) {
      if (!okm[mf]) { A[mf] = zv; continue; }
      const unsigned short* s = (kt < 4)
          ? (p.hb + (size_t)nrow[mf] * HD + kt * 32 + q * 8)
          : (p.agghb + (size_t)nrow[mf] * HD + (kt - 4) * 32 + q * 8);
      A[mf] = *(const bf16x8*)s;
    }
#pragma unroll
    for (int nf = 0; nf < 8; ++nf)
      B[nf] = *(const bf16x8*)(p.w4t + (size_t)kt * 4096 + (nf * 16 + lid) * 32 + q * 8);
  };
  auto LD5 = [&](int kt, bf16x8 (&A)[2], bf16x8 (&B)[8]) {
#pragma unroll
    for (int mf = 0; mf < 2; ++mf)
      A[mf] = *(const bf16x8*)&At[(rbase + mf * 16 + lid) * LDA + kt * 32 + q * 8];
#pragma unroll
    for (int nf = 0; nf < 8; ++nf)
      B[nf] = *(const bf16x8*)(p.w5t + (size_t)kt * 4096 + (nf * 16 + lid) * 32 + q * 8);
  };

  f32x4 acc[2][8];
  bf16x8 A0[2], B0[8], A1[2], B1[8];

  // GEMM4: K=256 (8 k-tiles)
  ZACC();
  GEMM_PIPE(8, LD4);
  ln_silu_w(acc, p.b1, p.g1, p.bb1, lid);
  write_strip(acc, At, rbase, lid, q);  // t3 -> wave-private LDS

  // GEMM5: K=128
  ZACC();
  GEMM_PIPE(4, LD5);

  float biasc[8];
#pragma unroll
  for (int nf = 0; nf < 8; ++nf) biasc[nf] = p.b5[nf * 16 + lid];
#pragma unroll
  for (int mf = 0; mf < 2; ++mf)
#pragma unroll
    for (int rg = 0; rg < 4; ++rg) {
      const int n = row0 + rbase + mf * 16 + q * 4 + rg;
      if (n < NN) {
#pragma unroll
        for (int nf = 0; nf < 8; ++nf) {
          const int c = nf * 16 + lid;
          const float v = acc[mf][nf][rg] + biasc[nf] + p.hf[(size_t)n * HD + c];
          p.hf_out[(size_t)n * HD + c] = v;
          p.hb_out[(size_t)n * HD + c] = f2b(v);
        }
      }
    }
}

// ---------------- host ----------------

extern "C" void kernel_launch(void* const* d_in, const int* in_sizes, int n_in,
                              void* d_out, int out_size, void* d_ws, size_t ws_size,
                              hipStream_t stream) {
  (void)in_sizes; (void)n_in; (void)out_size; (void)ws_size;
  const float* x_in = (const float*)d_in[0];
  const float* h_in = (const float*)d_in[1];
  const int* edges = (const int*)d_in[2];
  const float* eattr = (const float*)d_in[3];
  const float* emb_w = (const float*)d_in[4];
  const float* emb_b = (const float*)d_in[5];
  const float* out_w = (const float*)d_in[6];
  const float* out_b = (const float*)d_in[7];
  const float* pe_w1 = (const float*)d_in[8];
  const float* pe_b1 = (const float*)d_in[9];
  const float* pe_g1 = (const float*)d_in[10];
  const float* pe_bb1 = (const float*)d_in[11];
  const float* pe_w2 = (const float*)d_in[12];
  const float* pe_b2 = (const float*)d_in[13];
  const float* pe_g2 = (const float*)d_in[14];
  const float* pe_bb2 = (const float*)d_in[15];
  const float* px_w1 = (const float*)d_in[16];
  const float* px_b1 = (const float*)d_in[17];
  const float* px_g1 = (const float*)d_in[18];
  const float* px_bb1 = (const float*)d_in[19];
  const float* px_w2 = (const float*)d_in[20];
  const float* px_b2 = (const float*)d_in[21];
  const float* ph_w1 = (const float*)d_in[22];
  const float* ph_b1 = (const float*)d_in[23];
  const float* ph_g1 = (const float*)d_in[24];
  const float* ph_bb1 = (const float*)d_in[25];
  const float* ph_w2 = (const float*)d_in[26];
  const float* ph_b2 = (const float*)d_in[27];
  float* out = (float*)d_out;

  char* ws = (char*)d_ws;
  size_t off = 0;
  auto alloc = [&](size_t bytes) -> void* {
    void* ptr = ws + off;
    off = (off + bytes + 255) & ~(size_t)255;
    return ptr;
  };
  float* hf = (float*)alloc((size_t)NN * HD * 4);
  unsigned short* hb = (unsigned short*)alloc((size_t)NN * HD * 2);
  unsigned short* agghb = (unsigned short*)alloc((size_t)NN * HD * 2);
  float* xf = (float*)alloc((size_t)NN * 3 * 4);
  float* cinv = (float*)alloc((size_t)NN * 4);
  float* dvec = (float*)alloc((size_t)NE * 4 * 4);
  unsigned short* e8 = (unsigned short*)alloc((size_t)NE * 8 * 2);
  unsigned short* tbuf = (unsigned short*)alloc((size_t)NE * HD * 2);
  float* sc = (float*)alloc((size_t)NE * 4);
  int* deg = (int*)alloc((size_t)NN * 4);
  int* cursor = (int*)alloc((size_t)NN * 4);
  int* rowptr = (int*)alloc((size_t)(NN + 1) * 4);
  int* eids = (int*)alloc((size_t)NE * 4);
  unsigned short* w1t = (unsigned short*)alloc((size_t)NL * 9 * 4096 * 2);
  unsigned short* w2t = (unsigned short*)alloc((size_t)NL * 4 * 4096 * 2);
  unsigned short* w3t = (unsigned short*)alloc((size_t)NL * 4 * 4096 * 2);
  unsigned short* w4t = (unsigned short*)alloc((size_t)NL * 8 * 4096 * 2);
  unsigned short* w5t = (unsigned short*)alloc((size_t)NL * 4 * 4096 * 2);

  prep_zero_k<<<(NN * 3 + 255) / 256, 256, 0, stream>>>(x_in, xf, cinv, deg);
  count_k<<<(NE + 255) / 256, 256, 0, stream>>>(edges, cinv, deg);
  inv_k<<<(NN + 255) / 256, 256, 0, stream>>>(cinv);
  scan_k<<<1, 256, 0, stream>>>(deg, rowptr, cursor);
  scatter_k<<<(NE + 255) / 256, 256, 0, stream>>>(edges, cursor, eids);
  prep_w_k<<<(NL * 9 * 4096 + 255) / 256, 256, 0, stream>>>(pe_w1, w1t, 9, 261);
  prep_w_k<<<(NL * 4 * 4096 + 255) / 256, 256, 0, stream>>>(pe_w2, w2t, 4, 128);
  prep_w_k<<<(NL * 4 * 4096 + 255) / 256, 256, 0, stream>>>(px_w1, w3t, 4, 128);
  prep_w_k<<<(NL * 8 * 4096 + 255) / 256, 256, 0, stream>>>(ph_w1, w4t, 8, 256);
  prep_w_k<<<(NL * 4 * 4096 + 255) / 256, 256, 0, stream>>>(ph_w2, w5t, 4, 128);
  emb_k<<<(NN * HD + 255) / 256, 256, 0, stream>>>(h_in, emb_w, emb_b, hf, hb);

  const int egrid = NE / 128;          // 2500 (128 edges per block, 4 waves)
  const int ngrid = (NN + 63) / 64;    // 313 (64 nodes per block, 2 waves)

  for (int l = 0; l < NL; ++l) {
    prepd_k<<<(NE + 255) / 256, 256, 0, stream>>>(xf, edges, eattr, dvec, e8);
    {
      EP p{};
      p.hb = hb; p.e8 = e8; p.edges = edges;
      p.w1 = w1t + (size_t)l * 9 * 4096;
      p.w2 = w2t + (size_t)l * 4 * 4096;
      p.w3 = w3t + (size_t)l * 4 * 4096;
      p.b1 = pe_b1 + l * HD; p.g1 = pe_g1 + l * HD; p.bb1 = pe_bb1 + l * HD;
      p.b2 = pe_b2 + l * HD; p.g2 = pe_g2 + l * HD; p.bb2 = pe_bb2 + l * HD;
      p.b3 = px_b1 + l * HD; p.g3 = px_g1 + l * HD; p.bb3 = px_bb1 + l * HD;
      p.w4 = px_w2 + l * HD; p.b4 = px_b2 + l;
      p.tbuf = tbuf; p.sc = sc;
      edge_k<<<egrid, 256, 0, stream>>>(p);
    }
    gather_k<<<(NN + 3) / 4, 256, 0, stream>>>(tbuf, sc, dvec, rowptr, eids, cinv, agghb, xf);
    {
      NP p{};
      p.hf = hf; p.hb = hb; p.agghb = agghb;
      p.w4t = w4t + (size_t)l * 8 * 4096;
      p.w5t = w5t + (size_t)l * 4 * 4096;
      p.b1 = ph_b1 + l * HD; p.g1 = ph_g1 + l * HD; p.bb1 = ph_bb1 + l * HD;
      p.b5 = ph_b2 + l * HD;
      p.hf_out = hf; p.hb_out = hb;
      node_k<<<ngrid, 128, 0, stream>>>(p);
    }
  }

  outproj_k<<<(NN * OUTD + 255) / 256, 256, 0, stream>>>(hf, out_w, out_b, out);
  xcopy_k<<<(NN * 3 + 255) / 256, 256, 0, stream>>>(xf, out);
}

// Round 14
// 1185.297 us; speedup vs baseline: 1.0357x; 1.0357x over previous
//
#include <hip/hip_runtime.h>
#include <hip/hip_bf16.h>

#define NN 20000
#define NE 320000
#define HD 128
#define IND 16
#define OUTD 16
#define NL 4
#define LN_EPS 1e-5f
#define LDA 136  // LDS row stride in shorts (272B): 16B-aligned rows, ~2-way banks

typedef __attribute__((ext_vector_type(8))) short bf16x8;
typedef __attribute__((ext_vector_type(4))) float f32x4;

__device__ __forceinline__ unsigned short f2b(float f) {
  __hip_bfloat16 h = __float2bfloat16(f);
  unsigned short u;
  __builtin_memcpy(&u, &h, 2);
  return u;
}
__device__ __forceinline__ float b2f(unsigned int lo16) {
  union { unsigned int u; float f; } v; v.u = lo16 << 16; return v.f;
}

// ---------------- prep kernels ----------------

__global__ void prep_zero_k(const float* __restrict__ xin, float* __restrict__ xf,
                            float* __restrict__ cnt, int* __restrict__ deg) {
  int i = blockIdx.x * 256 + threadIdx.x;
  if (i < NN * 3) xf[i] = xin[i];
  if (i < NN) { cnt[i] = 0.f; deg[i] = 0; }
}

__global__ void count_k(const int* __restrict__ edges, float* __restrict__ cnt,
                        int* __restrict__ deg) {
  int e = blockIdx.x * 256 + threadIdx.x;
  if (e < NE) {
    atomicAdd(&cnt[edges[e]], 1.f);
    atomicAdd(&deg[edges[NE + e]], 1);
  }
}

__global__ void inv_k(float* __restrict__ cnt) {
  int n = blockIdx.x * 256 + threadIdx.x;
  if (n < NN) { float c = cnt[n]; cnt[n] = (c > 0.f) ? 1.f / c : 0.f; }
}

__global__ void scan_k(const int* __restrict__ deg, int* __restrict__ rowptr,
                       int* __restrict__ cursor) {
  __shared__ int part[256];
  const int tid = threadIdx.x;
  const int base = tid * 79;
  int s = 0;
  for (int t = 0; t < 79; ++t) { int idx = base + t; if (idx < NN) s += deg[idx]; }
  part[tid] = s;
  __syncthreads();
  for (int off = 1; off < 256; off <<= 1) {
    int v = (tid >= off) ? part[tid - off] : 0;
    __syncthreads();
    part[tid] += v;
    __syncthreads();
  }
  int run = (tid == 0) ? 0 : part[tid - 1];
  for (int t = 0; t < 79; ++t) {
    int idx = base + t;
    if (idx < NN) { rowptr[idx] = run; cursor[idx] = run; run += deg[idx]; }
  }
  if (tid == 255) rowptr[NN] = run;
}

__global__ void scatter_k(const int* __restrict__ edges, int* __restrict__ cursor,
                          int* __restrict__ eids) {
  int e = blockIdx.x * 256 + threadIdx.x;
  if (e < NE) {
    int d = edges[NE + e];
    int pos = atomicAdd(&cursor[d], 1);
    eids[pos] = e;
  }
}

// all five weight tensors: f32 [NL][Kreal][128] -> bf16 tiled [NL][KT][128][32]
__global__ void prep_w_all_k(const float* __restrict__ pe_w1, const float* __restrict__ pe_w2,
                             const float* __restrict__ px_w1, const float* __restrict__ ph_w1,
                             const float* __restrict__ ph_w2,
                             unsigned short* __restrict__ w1t, unsigned short* __restrict__ w2t,
                             unsigned short* __restrict__ w3t, unsigned short* __restrict__ w4t,
                             unsigned short* __restrict__ w5t) {
  const int G1 = NL * 9 * 4096, G2 = G1 + NL * 4 * 4096, G3 = G2 + NL * 4 * 4096,
            G4 = G3 + NL * 8 * 4096, G5 = G4 + NL * 4 * 4096;
  int i = blockIdx.x * 256 + threadIdx.x;
  const float* src; unsigned short* dst; int KT, Kreal, li;
  if (i < G1)      { src = pe_w1; dst = w1t; KT = 9; Kreal = 261; li = i; }
  else if (i < G2) { src = pe_w2; dst = w2t; KT = 4; Kreal = 128; li = i - G1; }
  else if (i < G3) { src = px_w1; dst = w3t; KT = 4; Kreal = 128; li = i - G2; }
  else if (i < G4) { src = ph_w1; dst = w4t; KT = 8; Kreal = 256; li = i - G3; }
  else if (i < G5) { src = ph_w2; dst = w5t; KT = 4; Kreal = 128; li = i - G4; }
  else return;
  const int kk = li & 31, c = (li >> 5) & 127, lkt = li >> 12;
  const int kt = lkt % KT, l = lkt / KT, k = kt * 32 + kk;
  const float v = (k < Kreal) ? src[((size_t)l * Kreal + k) * HD + c] : 0.f;
  dst[li] = f2b(v);
}

__global__ void emb_k(const float* __restrict__ hin, const float* __restrict__ w,
                      const float* __restrict__ b, float* __restrict__ hf,
                      unsigned short* __restrict__ hb) {
  int i = blockIdx.x * 256 + threadIdx.x;
  if (i >= NN * HD) return;
  int n = i >> 7, c = i & 127;
  float acc = b[c];
#pragma unroll
  for (int k = 0; k < IND; ++k) acc += hin[n * IND + k] * w[k * HD + c];
  hf[i] = acc;
  hb[i] = f2b(acc);
}

__global__ void outproj_k(const float* __restrict__ hf, const float* __restrict__ w,
                          const float* __restrict__ b, float* __restrict__ out) {
  int i = blockIdx.x * 256 + threadIdx.x;
  if (i >= NN * OUTD) return;
  int n = i >> 4, o = i & 15;
  float acc = b[o];
#pragma unroll 8
  for (int k = 0; k < HD; ++k) acc += hf[(size_t)n * HD + k] * w[k * OUTD + o];
  out[NN * 3 + i] = acc;
}

__global__ void xcopy_k(const float* __restrict__ xf, float* __restrict__ out) {
  int i = blockIdx.x * 256 + threadIdx.x;
  if (i < NN * 3) out[i] = xf[i];
}

// ---------------- CSR gather: agg_h (bf16) + agg_x (from mx) + x update ----------------

__global__ __launch_bounds__(256) void gather_k(const unsigned short* __restrict__ tbuf,
                                                const float* __restrict__ mx,
                                                const int* __restrict__ rowptr,
                                                const int* __restrict__ eids,
                                                const float* __restrict__ cinv,
                                                unsigned short* __restrict__ agghb,
                                                float* __restrict__ xf) {
  const int n = blockIdx.x * 4 + (threadIdx.x >> 6);
  if (n >= NN) return;
  const int lane = threadIdx.x & 63;
  const int s = rowptr[n], e = rowptr[n + 1];
  float a0 = 0.f, a1 = 0.f, b0 = 0.f, b1 = 0.f, xa = 0.f, xb = 0.f;
  int t = s;
  for (; t + 4 <= e; t += 4) {
    const int e0 = eids[t], e1 = eids[t + 1], e2 = eids[t + 2], e3 = eids[t + 3];
    const unsigned int v0 = *(const unsigned int*)(tbuf + (size_t)e0 * HD + lane * 2);
    const unsigned int v1 = *(const unsigned int*)(tbuf + (size_t)e1 * HD + lane * 2);
    const unsigned int v2 = *(const unsigned int*)(tbuf + (size_t)e2 * HD + lane * 2);
    const unsigned int v3 = *(const unsigned int*)(tbuf + (size_t)e3 * HD + lane * 2);
    a0 += b2f(v0 & 0xffffu) + b2f(v1 & 0xffffu);
    b0 += b2f(v2 & 0xffffu) + b2f(v3 & 0xffffu);
    a1 += b2f(v0 >> 16) + b2f(v1 >> 16);
    b1 += b2f(v2 >> 16) + b2f(v3 >> 16);
    if (lane < 3) {
      xa += mx[(size_t)e0 * 3 + lane] + mx[(size_t)e1 * 3 + lane];
      xb += mx[(size_t)e2 * 3 + lane] + mx[(size_t)e3 * 3 + lane];
    }
  }
  for (; t < e; ++t) {
    const int eid = eids[t];
    const unsigned int v = *(const unsigned int*)(tbuf + (size_t)eid * HD + lane * 2);
    a0 += b2f(v & 0xffffu);
    a1 += b2f(v >> 16);
    if (lane < 3) xa += mx[(size_t)eid * 3 + lane];
  }
  a0 += b0; a1 += b1; xa += xb;
  const unsigned int pk = (unsigned int)f2b(a0) | ((unsigned int)f2b(a1) << 16);
  *(unsigned int*)(agghb + (size_t)n * HD + lane * 2) = pk;
  if (lane < 3) xf[n * 3 + lane] += xa * cinv[n];
}

// ---------------- wave-strip GEMM pieces (wave owns 32 rows x 128 cols) ----------------

__device__ __forceinline__ void mfma_w(const bf16x8 (&A)[2], const bf16x8 (&B)[8],
                                       f32x4 (&acc)[2][8]) {
#pragma unroll
  for (int mf = 0; mf < 2; ++mf)
#pragma unroll
    for (int nf = 0; nf < 8; ++nf)
      acc[mf][nf] = __builtin_amdgcn_mfma_f32_16x16x32_bf16(A[mf], B[nf], acc[mf][nf], 0, 0, 0);
}

#define ZACC()                                          \
  _Pragma("unroll") for (int a_ = 0; a_ < 2; ++a_)      \
  _Pragma("unroll") for (int b_ = 0; b_ < 8; ++b_)      \
      acc[a_][b_] = (f32x4){0.f, 0.f, 0.f, 0.f}

// depth-1-prefetch double-buffered K pipeline; audited: kt consumed exactly once.
#define GEMM_PIPE(NKT, LD)                              \
  LD(0, A0, B0);                                        \
  _Pragma("unroll") for (int kt = 0; kt < (NKT); ++kt) {\
    if ((kt & 1) == 0) {                                \
      if (kt + 1 < (NKT)) LD(kt + 1, A1, B1);           \
      mfma_w(A0, B0, acc);                              \
    } else {                                            \
      if (kt + 1 < (NKT)) LD(kt + 1, A0, B0);           \
      mfma_w(A1, B1, acc);                              \
    }                                                   \
  }

// bias + row-LayerNorm(128) + SiLU, fully wave-local (no LDS, no barrier).
__device__ __forceinline__ void ln_silu_w(f32x4 (&acc)[2][8], const float* bias,
                                          const float* g, const float* bb, int lid) {
  float biasc[8], gc[8], bbc[8];
#pragma unroll
  for (int nf = 0; nf < 8; ++nf) {
    const int c = nf * 16 + lid;
    biasc[nf] = bias[c]; gc[nf] = g[c]; bbc[nf] = bb[c];
  }
#pragma unroll
  for (int mf = 0; mf < 2; ++mf)
#pragma unroll
    for (int nf = 0; nf < 8; ++nf)
#pragma unroll
      for (int rg = 0; rg < 4; ++rg) acc[mf][nf][rg] += biasc[nf];

  float s_[2][4], ss_[2][4];
#pragma unroll
  for (int mf = 0; mf < 2; ++mf)
#pragma unroll
    for (int rg = 0; rg < 4; ++rg) {
      float a = 0.f, b = 0.f;
#pragma unroll
      for (int nf = 0; nf < 8; ++nf) { float v = acc[mf][nf][rg]; a += v; b += v * v; }
      s_[mf][rg] = a; ss_[mf][rg] = b;
    }
#pragma unroll
  for (int m = 1; m < 16; m <<= 1) {
#pragma unroll
    for (int mf = 0; mf < 2; ++mf)
#pragma unroll
      for (int rg = 0; rg < 4; ++rg) {
        s_[mf][rg] += __shfl_xor(s_[mf][rg], m);
        ss_[mf][rg] += __shfl_xor(ss_[mf][rg], m);
      }
  }
#pragma unroll
  for (int mf = 0; mf < 2; ++mf)
#pragma unroll
    for (int rg = 0; rg < 4; ++rg) {
      const float mu = s_[mf][rg] * (1.f / HD);
      const float var = ss_[mf][rg] * (1.f / HD) - mu * mu;
      const float rstd = rsqrtf(var + LN_EPS);
#pragma unroll
      for (int nf = 0; nf < 8; ++nf) {
        float v = acc[mf][nf][rg];
        v = (v - mu) * rstd * gc[nf] + bbc[nf];
        acc[mf][nf][rg] = v / (1.f + __expf(-v));
      }
    }
}

// write this wave's 32x128 C strip (bf16) into its private LDS rows
__device__ __forceinline__ void write_strip(const f32x4 (&acc)[2][8], unsigned short* At,
                                            int rbase, int lid, int q) {
#pragma unroll
  for (int mf = 0; mf < 2; ++mf)
#pragma unroll
    for (int rg = 0; rg < 4; ++rg) {
      const int row = rbase + mf * 16 + q * 4 + rg;
#pragma unroll
      for (int nf = 0; nf < 8; ++nf)
        At[row * LDA + nf * 16 + lid] = f2b(acc[mf][nf][rg]);
    }
}

// ---------------- fused edge kernel (ZERO barriers; prepd fused in) ----------------
// GEMM1(K=288: h[i]|h[j]|[d2,ea]) -> LN/SiLU -> GEMM2 -> LN/SiLU -> tbuf
// -> GEMM3 -> LN/SiLU -> dot(w4) -> mx = d*sc (direct).

struct EP {
  const unsigned short* hb;
  const float* xf;
  const float* ea;
  const int* edges;
  const unsigned short *w1, *w2, *w3;
  const float *b1, *g1, *bb1, *b2, *g2, *bb2, *b3, *g3, *bb3;
  const float *w4, *b4;
  unsigned short* tbuf;
  float* mx;
};

__global__ __launch_bounds__(256, 3) void edge_k(EP p) {
  __shared__ __align__(16) unsigned short At[128 * LDA];
  __shared__ float scSh[4][32];

  const int tid = threadIdx.x, lane = tid & 63, lid = lane & 15, q = lane >> 4;
  const int wave = tid >> 6;
  const int rbase = wave * 32;
  const int row0 = blockIdx.x * 128;

  int ei[2], ej[2];
#pragma unroll
  for (int mf = 0; mf < 2; ++mf) {
    const int r = row0 + rbase + mf * 16 + lid;
    ei[mf] = p.edges[NE + r];
    ej[mf] = p.edges[r];
  }

  const bf16x8 zv = {0, 0, 0, 0, 0, 0, 0, 0};

  auto LD1 = [&](int kt, bf16x8 (&A)[2], bf16x8 (&B)[8]) {
#pragma unroll
    for (int mf = 0; mf < 2; ++mf) {
      if (kt < 4)
        A[mf] = *(const bf16x8*)(p.hb + (size_t)ei[mf] * HD + kt * 32 + q * 8);
      else if (kt < 8)
        A[mf] = *(const bf16x8*)(p.hb + (size_t)ej[mf] * HD + (kt - 4) * 32 + q * 8);
      else if (q == 0) {
        const int e_ = row0 + rbase + mf * 16 + lid;
        const float* xi = p.xf + (size_t)ei[mf] * 3;
        const float* xj = p.xf + (size_t)ej[mf] * 3;
        const float dx = xi[0] - xj[0], dy = xi[1] - xj[1], dz = xi[2] - xj[2];
        const float d2 = dx * dx + dy * dy + dz * dz;
        const float4 eav = *(const float4*)(p.ea + (size_t)e_ * 4);
        unsigned short t_[8] = {f2b(d2), f2b(eav.x), f2b(eav.y), f2b(eav.z), f2b(eav.w), 0, 0, 0};
        A[mf] = *(const bf16x8*)t_;
      } else
        A[mf] = zv;
    }
#pragma unroll
    for (int nf = 0; nf < 8; ++nf)
      B[nf] = *(const bf16x8*)(p.w1 + (size_t)kt * 4096 + (nf * 16 + lid) * 32 + q * 8);
  };
  auto LDW = [&](const unsigned short* wt, int kt, bf16x8 (&A)[2], bf16x8 (&B)[8]) {
#pragma unroll
    for (int mf = 0; mf < 2; ++mf)
      A[mf] = *(const bf16x8*)&At[(rbase + mf * 16 + lid) * LDA + kt * 32 + q * 8];
#pragma unroll
    for (int nf = 0; nf < 8; ++nf)
      B[nf] = *(const bf16x8*)(wt + (size_t)kt * 4096 + (nf * 16 + lid) * 32 + q * 8);
  };
  auto LD2 = [&](int kt, bf16x8 (&A)[2], bf16x8 (&B)[8]) { LDW(p.w2, kt, A, B); };
  auto LD3 = [&](int kt, bf16x8 (&A)[2], bf16x8 (&B)[8]) { LDW(p.w3, kt, A, B); };

  f32x4 acc[2][8];
  bf16x8 A0[2], B0[8], A1[2], B1[8];

  // GEMM1: K=288 (9 k-tiles)
  ZACC();
  GEMM_PIPE(9, LD1);
  ln_silu_w(acc, p.b1, p.g1, p.bb1, lid);
  write_strip(acc, At, rbase, lid, q);  // t -> wave-private LDS rows

  // GEMM2: K=128
  ZACC();
  GEMM_PIPE(4, LD2);
  ln_silu_w(acc, p.b2, p.g2, p.bb2, lid);
  write_strip(acc, At, rbase, lid, q);  // mh -> LDS

  // mh copy-out: wave copies its own 32 rows (16B granules, coalesced)
#pragma unroll
  for (int it = 0; it < 8; ++it) {
    const int idx = it * 64 + lane;
    const int row = idx >> 4, sl = idx & 15;
    const uint4 v = *(const uint4*)&At[(rbase + row) * LDA + sl * 8];
    *(uint4*)(p.tbuf + (size_t)(row0 + rbase + row) * HD + sl * 8) = v;
  }

  // GEMM3: K=128
  ZACC();
  GEMM_PIPE(4, LD3);
  ln_silu_w(acc, p.b3, p.g3, p.bb3, lid);

  // sc = dot(t2_row, w4) + b4 — wave-local reduce
  float w4c[8];
#pragma unroll
  for (int nf = 0; nf < 8; ++nf) w4c[nf] = p.w4[nf * 16 + lid];
  float dp[2][4];
#pragma unroll
  for (int mf = 0; mf < 2; ++mf)
#pragma unroll
    for (int rg = 0; rg < 4; ++rg) {
      float a = 0.f;
#pragma unroll
      for (int nf = 0; nf < 8; ++nf) a += acc[mf][nf][rg] * w4c[nf];
      dp[mf][rg] = a;
    }
#pragma unroll
  for (int m = 1; m < 16; m <<= 1) {
#pragma unroll
    for (int mf = 0; mf < 2; ++mf)
#pragma unroll
      for (int rg = 0; rg < 4; ++rg) dp[mf][rg] += __shfl_xor(dp[mf][rg], m);
  }
  // broadcast sc lane->row via wave-local LDS (no barrier: per-wave LDS is in-order)
  if (lid == 0) {
    const float b4 = p.b4[0];
#pragma unroll
    for (int mf = 0; mf < 2; ++mf)
#pragma unroll
      for (int rg = 0; rg < 4; ++rg)
        scSh[wave][mf * 16 + q * 4 + rg] = dp[mf][rg] + b4;
  }
  asm volatile("" ::: "memory");  // keep ds_write before ds_read in program order
  if (q == 0) {
#pragma unroll
    for (int mf = 0; mf < 2; ++mf) {
      const int e_ = row0 + rbase + mf * 16 + lid;
      const float scv = scSh[wave][mf * 16 + lid];
      const float* xi = p.xf + (size_t)ei[mf] * 3;
      const float* xj = p.xf + (size_t)ej[mf] * 3;
      p.mx[(size_t)e_ * 3 + 0] = (xi[0] - xj[0]) * scv;
      p.mx[(size_t)e_ * 3 + 1] = (xi[1] - xj[1]) * scv;
      p.mx[(size_t)e_ * 3 + 2] = (xi[2] - xj[2]) * scv;
    }
  }
}

// ---------------- fused node kernel (ZERO barriers, 64-row blocks, bf16 A) ----------------

struct NP {
  const float* hf;
  const unsigned short* hb;
  const unsigned short* agghb;
  const unsigned short *w4t, *w5t;
  const float *b1, *g1, *bb1, *b5;
  float* hf_out;
  unsigned short* hb_out;
};

__global__ __launch_bounds__(128, 3) void node_k(NP p) {
  __shared__ __align__(16) unsigned short At[64 * LDA];

  const int tid = threadIdx.x, lane = tid & 63, lid = lane & 15, q = lane >> 4;
  const int wave = tid >> 6;  // 0..1
  const int rbase = wave * 32;
  const int row0 = blockIdx.x * 64;

  int nrow[2];
  bool okm[2];
#pragma unroll
  for (int mf = 0; mf < 2; ++mf) {
    nrow[mf] = row0 + rbase + mf * 16 + lid;
    okm[mf] = nrow[mf] < NN;
  }

  const bf16x8 zv = {0, 0, 0, 0, 0, 0, 0, 0};

  auto LD4 = [&](int kt, bf16x8 (&A)[2], bf16x8 (&B)[8]) {
#pragma unroll
    for (int mf = 0; mf < 2; ++mf) {
      if (!okm[mf]) { A[mf] = zv; continue; }
      const unsigned short* s = (kt < 4)
          ? (p.hb + (size_t)nrow[mf] * HD + kt * 32 + q * 8)
          : (p.agghb + (size_t)nrow[mf] * HD + (kt - 4) * 32 + q * 8);
      A[mf] = *(const bf16x8*)s;
    }
#pragma unroll
    for (int nf = 0; nf < 8; ++nf)
      B[nf] = *(const bf16x8*)(p.w4t + (size_t)kt * 4096 + (nf * 16 + lid) * 32 + q * 8);
  };
  auto LD5 = [&](int kt, bf16x8 (&A)[2], bf16x8 (&B)[8]) {
#pragma unroll
    for (int mf = 0; mf < 2; ++mf)
      A[mf] = *(const bf16x8*)&At[(rbase + mf * 16 + lid) * LDA + kt * 32 + q * 8];
#pragma unroll
    for (int nf = 0; nf < 8; ++nf)
      B[nf] = *(const bf16x8*)(p.w5t + (size_t)kt * 4096 + (nf * 16 + lid) * 32 + q * 8);
  };

  f32x4 acc[2][8];
  bf16x8 A0[2], B0[8], A1[2], B1[8];

  // GEMM4: K=256 (8 k-tiles)
  ZACC();
  GEMM_PIPE(8, LD4);
  ln_silu_w(acc, p.b1, p.g1, p.bb1, lid);
  write_strip(acc, At, rbase, lid, q);  // t3 -> wave-private LDS

  // GEMM5: K=128
  ZACC();
  GEMM_PIPE(4, LD5);

  float biasc[8];
#pragma unroll
  for (int nf = 0; nf < 8; ++nf) biasc[nf] = p.b5[nf * 16 + lid];
#pragma unroll
  for (int mf = 0; mf < 2; ++mf)
#pragma unroll
    for (int rg = 0; rg < 4; ++rg) {
      const int n = row0 + rbase + mf * 16 + q * 4 + rg;
      if (n < NN) {
#pragma unroll
        for (int nf = 0; nf < 8; ++nf) {
          const int c = nf * 16 + lid;
          const float v = acc[mf][nf][rg] + biasc[nf] + p.hf[(size_t)n * HD + c];
          p.hf_out[(size_t)n * HD + c] = v;
          p.hb_out[(size_t)n * HD + c] = f2b(v);
        }
      }
    }
}

// ---------------- host ----------------

extern "C" void kernel_launch(void* const* d_in, const int* in_sizes, int n_in,
                              void* d_out, int out_size, void* d_ws, size_t ws_size,
                              hipStream_t stream) {
  (void)in_sizes; (void)n_in; (void)out_size; (void)ws_size;
  const float* x_in = (const float*)d_in[0];
  const float* h_in = (const float*)d_in[1];
  const int* edges = (const int*)d_in[2];
  const float* eattr = (const float*)d_in[3];
  const float* emb_w = (const float*)d_in[4];
  const float* emb_b = (const float*)d_in[5];
  const float* out_w = (const float*)d_in[6];
  const float* out_b = (const float*)d_in[7];
  const float* pe_w1 = (const float*)d_in[8];
  const float* pe_b1 = (const float*)d_in[9];
  const float* pe_g1 = (const float*)d_in[10];
  const float* pe_bb1 = (const float*)d_in[11];
  const float* pe_w2 = (const float*)d_in[12];
  const float* pe_b2 = (const float*)d_in[13];
  const float* pe_g2 = (const float*)d_in[14];
  const float* pe_bb2 = (const float*)d_in[15];
  const float* px_w1 = (const float*)d_in[16];
  const float* px_b1 = (const float*)d_in[17];
  const float* px_g1 = (const float*)d_in[18];
  const float* px_bb1 = (const float*)d_in[19];
  const float* px_w2 = (const float*)d_in[20];
  const float* px_b2 = (const float*)d_in[21];
  const float* ph_w1 = (const float*)d_in[22];
  const float* ph_b1 = (const float*)d_in[23];
  const float* ph_g1 = (const float*)d_in[24];
  const float* ph_bb1 = (const float*)d_in[25];
  const float* ph_w2 = (const float*)d_in[26];
  const float* ph_b2 = (const float*)d_in[27];
  float* out = (float*)d_out;

  char* ws = (char*)d_ws;
  size_t off = 0;
  auto alloc = [&](size_t bytes) -> void* {
    void* ptr = ws + off;
    off = (off + bytes + 255) & ~(size_t)255;
    return ptr;
  };
  float* hf = (float*)alloc((size_t)NN * HD * 4);
  unsigned short* hb = (unsigned short*)alloc((size_t)NN * HD * 2);
  unsigned short* agghb = (unsigned short*)alloc((size_t)NN * HD * 2);
  float* xf = (float*)alloc((size_t)NN * 3 * 4);
  float* cinv = (float*)alloc((size_t)NN * 4);
  unsigned short* tbuf = (unsigned short*)alloc((size_t)NE * HD * 2);
  float* mx = (float*)alloc((size_t)NE * 3 * 4);
  int* deg = (int*)alloc((size_t)NN * 4);
  int* cursor = (int*)alloc((size_t)NN * 4);
  int* rowptr = (int*)alloc((size_t)(NN + 1) * 4);
  int* eids = (int*)alloc((size_t)NE * 4);
  unsigned short* w1t = (unsigned short*)alloc((size_t)NL * 9 * 4096 * 2);
  unsigned short* w2t = (unsigned short*)alloc((size_t)NL * 4 * 4096 * 2);
  unsigned short* w3t = (unsigned short*)alloc((size_t)NL * 4 * 4096 * 2);
  unsigned short* w4t = (unsigned short*)alloc((size_t)NL * 8 * 4096 * 2);
  unsigned short* w5t = (unsigned short*)alloc((size_t)NL * 4 * 4096 * 2);

  prep_zero_k<<<(NN * 3 + 255) / 256, 256, 0, stream>>>(x_in, xf, cinv, deg);
  count_k<<<(NE + 255) / 256, 256, 0, stream>>>(edges, cinv, deg);
  inv_k<<<(NN + 255) / 256, 256, 0, stream>>>(cinv);
  scan_k<<<1, 256, 0, stream>>>(deg, rowptr, cursor);
  scatter_k<<<(NE + 255) / 256, 256, 0, stream>>>(edges, cursor, eids);
  {
    const int total = NL * (9 + 4 + 4 + 8 + 4) * 4096;
    prep_w_all_k<<<(total + 255) / 256, 256, 0, stream>>>(pe_w1, pe_w2, px_w1, ph_w1, ph_w2,
                                                          w1t, w2t, w3t, w4t, w5t);
  }
  emb_k<<<(NN * HD + 255) / 256, 256, 0, stream>>>(h_in, emb_w, emb_b, hf, hb);

  const int egrid = NE / 128;          // 2500 (128 edges per block, 4 waves)
  const int ngrid = (NN + 63) / 64;    // 313 (64 nodes per block, 2 waves)

  for (int l = 0; l < NL; ++l) {
    {
      EP p{};
      p.hb = hb; p.xf = xf; p.ea = eattr; p.edges = edges;
      p.w1 = w1t + (size_t)l * 9 * 4096;
      p.w2 = w2t + (size_t)l * 4 * 4096;
      p.w3 = w3t + (size_t)l * 4 * 4096;
      p.b1 = pe_b1 + l * HD; p.g1 = pe_g1 + l * HD; p.bb1 = pe_bb1 + l * HD;
      p.b2 = pe_b2 + l * HD; p.g2 = pe_g2 + l * HD; p.bb2 = pe_bb2 + l * HD;
      p.b3 = px_b1 + l * HD; p.g3 = px_g1 + l * HD; p.bb3 = px_bb1 + l * HD;
      p.w4 = px_w2 + l * HD; p.b4 = px_b2 + l;
      p.tbuf = tbuf; p.mx = mx;
      edge_k<<<egrid, 256, 0, stream>>>(p);
    }
    gather_k<<<(NN + 3) / 4, 256, 0, stream>>>(tbuf, mx, rowptr, eids, cinv, agghb, xf);
    {
      NP p{};
      p.hf = hf; p.hb = hb; p.agghb = agghb;
      p.w4t = w4t + (size_t)l * 8 * 4096;
      p.w5t = w5t + (size_t)l * 4 * 4096;
      p.b1 = ph_b1 + l * HD; p.g1 = ph_g1 + l * HD; p.bb1 = ph_bb1 + l * HD;
      p.b5 = ph_b2 + l * HD;
      p.hf_out = hf; p.hb_out = hb;
      node_k<<<ngrid, 128, 0, stream>>>(p);
    }
  }

  outproj_k<<<(NN * OUTD + 255) / 256, 256, 0, stream>>>(hf, out_w, out_b, out);
  xcopy_k<<<(NN * 3 + 255) / 256, 256, 0, stream>>>(xf, out);
}